// Round 10
// baseline (183.893 us; speedup 1.0000x reference)
//
#include <hip/hip_runtime.h>
#include <hip/hip_bf16.h>

#define N_ROWS 8192
#define N_HALF 4096
#define DIM    2048
#define INV_T  2.0f   // 1/TEMP, TEMP=0.5
#define NG1    1024   // full tiles: sum_{bi}(63-2*bi), bj in [2bi, 63)
#define NG2    256    // tail: 32 tiles (bj=63) M-split x8 (32-row blocks)
#define NPH    64     // DIM / 32 K-phases

typedef __attribute__((ext_vector_type(8))) short bf16x8;
typedef __attribute__((ext_vector_type(4))) float f32x4;

__device__ __forceinline__ float bf2f(short s) {
  return __uint_as_float(((unsigned int)(unsigned short)s) << 16);
}

__device__ __forceinline__ short f2bf(float x) {
  unsigned int u = __float_as_uint(x);
  u += 0x7fffu + ((u >> 16) & 1u);
  return (short)(u >> 16);
}

__device__ __forceinline__ void gload_lds16(const void* g, void* l) {
  __builtin_amdgcn_global_load_lds(
      (const __attribute__((address_space(1))) unsigned int*)g,
      (__attribute__((address_space(3))) unsigned int*)l, 16, 0, 0);
}

// ---------------------------------------------------------------------------
// Kernel 1: fused normalize + positives + self-dots (round-9 verbatim).
// ---------------------------------------------------------------------------
__global__ __launch_bounds__(256) void normpos_k(
    const float* __restrict__ xi, const float* __restrict__ xj,
    short* __restrict__ z, float* __restrict__ pos,
    float* __restrict__ selfd)
{
  const int b = blockIdx.x;            // 0..4095
  const int t = threadIdx.x;
  const float4* si = (const float4*)(xi + (size_t)b * DIM);
  const float4* sj = (const float4*)(xj + (size_t)b * DIM);
  float4 a0 = si[t * 2], a1 = si[t * 2 + 1];
  float4 c0 = sj[t * 2], c1 = sj[t * 2 + 1];
  float ssi = a0.x*a0.x + a0.y*a0.y + a0.z*a0.z + a0.w*a0.w
            + a1.x*a1.x + a1.y*a1.y + a1.z*a1.z + a1.w*a1.w;
  float ssj = c0.x*c0.x + c0.y*c0.y + c0.z*c0.z + c0.w*c0.w
            + c1.x*c1.x + c1.y*c1.y + c1.z*c1.z + c1.w*c1.w;
  #pragma unroll
  for (int m = 1; m < 64; m <<= 1) {
    ssi += __shfl_xor(ssi, m, 64);
    ssj += __shfl_xor(ssj, m, 64);
  }
  __shared__ float ri[4], rj[4];
  if ((t & 63) == 0) { ri[t >> 6] = ssi; rj[t >> 6] = ssj; }
  __syncthreads();
  float sci = 1.0f / fmaxf(sqrtf(ri[0] + ri[1] + ri[2] + ri[3]), 1e-12f);
  float scj = 1.0f / fmaxf(sqrtf(rj[0] + rj[1] + rj[2] + rj[3]), 1e-12f);

  float fi[8] = {a0.x, a0.y, a0.z, a0.w, a1.x, a1.y, a1.z, a1.w};
  float fj[8] = {c0.x, c0.y, c0.z, c0.w, c1.x, c1.y, c1.z, c1.w};
  bf16x8 pi, pj;
  float dp = 0.f, dsi = 0.f, dsj = 0.f;
  #pragma unroll
  for (int e = 0; e < 8; ++e) {
    short qi = f2bf(fi[e] * sci), qj = f2bf(fj[e] * scj);
    pi[e] = qi; pj[e] = qj;
    float vi = bf2f(qi), vj = bf2f(qj);
    dp  += vi * vj;
    dsi += vi * vi;
    dsj += vj * vj;
  }
  *((bf16x8*)(z + (size_t)b * DIM) + t)            = pi;
  *((bf16x8*)(z + (size_t)(b + N_HALF) * DIM) + t) = pj;

  #pragma unroll
  for (int m = 1; m < 64; m <<= 1) {
    dp  += __shfl_xor(dp, m, 64);
    dsi += __shfl_xor(dsi, m, 64);
    dsj += __shfl_xor(dsj, m, 64);
  }
  __shared__ float rp[4], rsi[4], rsj[4];
  if ((t & 63) == 0) { rp[t >> 6] = dp; rsi[t >> 6] = dsi; rsj[t >> 6] = dsj; }
  __syncthreads();
  if (t == 0) {
    float p = rp[0] + rp[1] + rp[2] + rp[3];
    pos[b]           = p;
    pos[b + N_HALF]  = p;
    selfd[b]          = rsi[0] + rsi[1] + rsi[2] + rsi[3];
    selfd[b + N_HALF] = rsj[0] + rsj[1] + rsj[2] + rsj[3];
  }
}

// ---------------------------------------------------------------------------
// Kernel 2: symmetric fused sim-tile + exp row/col sums.  UNIFIED dispatch
// (round-9 geometry), but 4 WAVES / 256 threads per block, per-wave 128x64
// output (a[8] x b[4] = 32 MFMA/phase: 42.7 FLOP per LDS-byte vs 32 before
// — LDS-read is the phase critical path).
//  bids [0,1024): full 256x128 tiles, bands bi x bj in [2bi,63).
//  bids [1024,1280): tail — bj=63 tiles M-split x8 (32-row blocks, full K).
// 3-slot LDS rotation lead-2 (A 16K + B 8K = 72 KiB, 2 blocks/CU).
// STAGE = 6 gload_lds16 (4 KB each: A x4, B x2); steady vmcnt(6).
// Swizzle (both sides, linear gload dest): LDS row q=r>>1 (128 B),
// 16B slot s = ((r&1)*4 + k4) ^ (q&7).
// Row-sums always; col-sums iff tile right of band diag (full: bj>=2bi+2,
// tail: bi<=30).  Diagonal exp(self) subtracted in loss_k.
// ---------------------------------------------------------------------------
__global__ __launch_bounds__(256, 2) void simexp_k(
    const short* __restrict__ z, float* __restrict__ denom)
{
  __shared__ char lds[73728];
  char* ldsA = lds;            // 3 x 16384
  char* ldsB = lds + 49152;    // 3 x 8192

  const int t    = threadIdx.x;
  const int wave = t >> 6, lane = t & 63;
  const int bid  = blockIdx.x;

  if (bid < NG1) {
    // ===================== FULL TILE PATH ================================
    const int wr = wave >> 1, wc = wave & 1;   // 2M x 2N wave grid

    int rem = (bid & 7) * (NG1 / 8) + (bid >> 3);   // XCD-bijective swizzle
    int bi = 0;
    while (rem >= 63 - 2 * bi) { rem -= 63 - 2 * bi; ++bi; }
    const int bj   = 2 * bi + rem;               // in [2bi, 63)
    const int row0 = bi * 256;
    const int col0 = bj * 128;

    // staging source offsets (swizzle-inverse of linear LDS dest).
    // 256 thr x 16B = 4 KiB per call = 64 logical rows.
    const int sq  = t >> 3;                     // 0..31
    const int ss0 = (t & 7) ^ (sq & 7);
    const int sr  = 2 * sq + (ss0 >> 2);        // 0..63
    const int sk4 = ss0 & 3;
    const short* zA = z + (size_t)(row0 + sr) * DIM + sk4 * 8;
    const short* zB = z + (size_t)(col0 + sr) * DIM + sk4 * 8;
    char* dA = ldsA + wave * 1024;              // wave-uniform dest bases
    char* dB = ldsB + wave * 1024;

    int offA[8], offB[4];
    #pragma unroll
    for (int m = 0; m < 8; ++m) {
      int r = wr * 128 + m * 16 + (lane & 15);
      int q = r >> 1;
      int s = ((lane >> 4) + (r & 1) * 4) ^ (q & 7);
      offA[m] = q * 128 + s * 16;
    }
    #pragma unroll
    for (int n = 0; n < 4; ++n) {
      int r = wc * 64 + n * 16 + (lane & 15);
      int q = r >> 1;
      int s = ((lane >> 4) + (r & 1) * 4) ^ (q & 7);
      offB[n] = q * 128 + s * 16;
    }

    f32x4 acc[8][4] = {};

#define STAGE(kh, slot) do {                                   \
      const short* pa_ = zA + (kh) * 32;                       \
      const short* pb_ = zB + (kh) * 32;                       \
      char* da_ = dA + (slot) * 16384;                         \
      char* db_ = dB + (slot) * 8192;                          \
      gload_lds16(pa_,             da_);                       \
      gload_lds16(pa_ +  64 * DIM, da_ + 4096);                \
      gload_lds16(pa_ + 128 * DIM, da_ + 8192);                \
      gload_lds16(pa_ + 192 * DIM, da_ + 12288);               \
      gload_lds16(pb_,             db_);                       \
      gload_lds16(pb_ +  64 * DIM, db_ + 4096);                \
    } while (0)

    STAGE(0, 0);
    STAGE(1, 1);

    int sl = 0;
    for (int p = 0; p < NPH; ++p) {
      if (p < NPH - 1) asm volatile("s_waitcnt vmcnt(6)" ::: "memory");
      else             asm volatile("s_waitcnt vmcnt(0)" ::: "memory");
      __builtin_amdgcn_s_barrier();
      __builtin_amdgcn_sched_barrier(0);

      const char* Ab = ldsA + sl * 16384;
      const char* Bb = ldsB + sl * 8192;
      bf16x8 a[8], b[4];
      #pragma unroll
      for (int m = 0; m < 8; ++m) a[m] = *(const bf16x8*)(Ab + offA[m]);
      #pragma unroll
      for (int n = 0; n < 4; ++n) b[n] = *(const bf16x8*)(Bb + offB[n]);

      if (p + 2 < NPH) {
        int s2 = sl + 2; if (s2 >= 3) s2 -= 3;   // slot (p+2)%3 == (p-1)%3
        STAGE(p + 2, s2);                        // readers passed barrier p
      }

      __builtin_amdgcn_s_setprio(1);
      #pragma unroll
      for (int m = 0; m < 8; ++m)
        #pragma unroll
        for (int n = 0; n < 4; ++n)
          acc[m][n] = __builtin_amdgcn_mfma_f32_16x16x32_bf16(a[m], b[n],
                                                              acc[m][n], 0, 0, 0);
      __builtin_amdgcn_s_setprio(0);
      __builtin_amdgcn_sched_barrier(0);

      if (++sl >= 3) sl = 0;
    }
#undef STAGE

    #pragma unroll
    for (int m = 0; m < 8; ++m)
      #pragma unroll
      for (int n = 0; n < 4; ++n)
        #pragma unroll
        for (int r = 0; r < 4; ++r)
          acc[m][n][r] = __expf(acc[m][n][r] * INV_T);

    // row sums: C layout col = lane&15, row = (lane>>4)*4 + reg
    #pragma unroll
    for (int m = 0; m < 8; ++m) {
      #pragma unroll
      for (int r = 0; r < 4; ++r) {
        float s = acc[m][0][r] + acc[m][1][r] + acc[m][2][r] + acc[m][3][r];
        s += __shfl_xor(s, 1, 64);
        s += __shfl_xor(s, 2, 64);
        s += __shfl_xor(s, 4, 64);
        s += __shfl_xor(s, 8, 64);
        if ((lane & 15) == 0) {
          int grow = row0 + wr * 128 + m * 16 + (lane >> 4) * 4 + r;
          atomicAdd(&denom[grow], s);
        }
      }
    }

    if (bj >= 2 * bi + 2) {
      #pragma unroll
      for (int n = 0; n < 4; ++n) {
        float cs = 0.f;
        #pragma unroll
        for (int m = 0; m < 8; ++m)
          #pragma unroll
          for (int r = 0; r < 4; ++r)
            cs += acc[m][n][r];
        cs += __shfl_xor(cs, 16, 64);
        cs += __shfl_xor(cs, 32, 64);
        if ((lane >> 4) == 0) {
          int gcol = col0 + wc * 64 + n * 16 + (lane & 15);
          atomicAdd(&denom[gcol], cs);
        }
      }
    }
  } else {
    // ===================== TAIL PATH: 32-row x 128-col, cols 8064.. =======
    const int sub  = bid - NG1;                // 0..255
    const int bi   = sub >> 3;                 // band 0..31
    const int row0 = bi * 256 + (sub & 7) * 32;
    const int col0 = 8064;

    // B staging: 2 calls of 4 KiB (rows 0-63, 64-127 of the col strip)
    const int sq  = t >> 3;
    const int ss0 = (t & 7) ^ (sq & 7);
    const int sr  = 2 * sq + (ss0 >> 2);
    const int sk4 = ss0 & 3;
    const short* zB = z + (size_t)(col0 + sr) * DIM + sk4 * 8;
    // A staging: threads 0..127 (waves 0-1) cover the 32 rows (2 KiB)
    const int tA   = t & 127;
    const int sqA  = tA >> 3;                  // 0..15
    const int ss0A = (tA & 7) ^ (sqA & 7);
    const int srA  = 2 * sqA + (ss0A >> 2);    // 0..31
    const int sk4A = ss0A & 3;
    const short* zAs = z + (size_t)(row0 + srA) * DIM + sk4A * 8;
    char* dA = ldsA + wave * 1024;             // waves 0-1 only
    char* dB = ldsB + wave * 1024;

    int offA2[2], offB2[2];
    #pragma unroll
    for (int m = 0; m < 2; ++m) {
      int r = m * 16 + (lane & 15);            // 0..31
      int q = r >> 1;
      int s = ((lane >> 4) + (r & 1) * 4) ^ (q & 7);
      offA2[m] = q * 128 + s * 16;
    }
    #pragma unroll
    for (int n = 0; n < 2; ++n) {
      int r = wave * 32 + n * 16 + (lane & 15); // 0..127
      int q = r >> 1;
      int s = ((lane >> 4) + (r & 1) * 4) ^ (q & 7);
      offB2[n] = q * 128 + s * 16;
    }

    f32x4 acc2[2][2] = {};

#define STAGE_T(kh, slot) do {                                 \
      gload_lds16(zB + (kh) * 32,            dB + (slot) * 8192);        \
      gload_lds16(zB + (kh) * 32 + 64 * DIM, dB + (slot) * 8192 + 4096); \
      if (wave < 2)                                            \
        gload_lds16(zAs + (kh) * 32, dA + (slot) * 16384);     \
    } while (0)

    STAGE_T(0, 0);
    STAGE_T(1, 1);

    int sl = 0;
    for (int p = 0; p < NPH; ++p) {
      if (p < NPH - 1) {
        if (wave < 2) asm volatile("s_waitcnt vmcnt(3)" ::: "memory");
        else          asm volatile("s_waitcnt vmcnt(2)" ::: "memory");
      } else {
        asm volatile("s_waitcnt vmcnt(0)" ::: "memory");
      }
      __builtin_amdgcn_s_barrier();
      __builtin_amdgcn_sched_barrier(0);

      const char* Ab = ldsA + sl * 16384;
      const char* Bb = ldsB + sl * 8192;
      bf16x8 a0 = *(const bf16x8*)(Ab + offA2[0]);
      bf16x8 a1 = *(const bf16x8*)(Ab + offA2[1]);
      bf16x8 b0 = *(const bf16x8*)(Bb + offB2[0]);
      bf16x8 b1 = *(const bf16x8*)(Bb + offB2[1]);

      if (p + 2 < NPH) {
        int s2 = sl + 2; if (s2 >= 3) s2 -= 3;
        STAGE_T(p + 2, s2);
      }

      __builtin_amdgcn_s_setprio(1);
      acc2[0][0] = __builtin_amdgcn_mfma_f32_16x16x32_bf16(a0, b0, acc2[0][0], 0, 0, 0);
      acc2[0][1] = __builtin_amdgcn_mfma_f32_16x16x32_bf16(a0, b1, acc2[0][1], 0, 0, 0);
      acc2[1][0] = __builtin_amdgcn_mfma_f32_16x16x32_bf16(a1, b0, acc2[1][0], 0, 0, 0);
      acc2[1][1] = __builtin_amdgcn_mfma_f32_16x16x32_bf16(a1, b1, acc2[1][1], 0, 0, 0);
      __builtin_amdgcn_s_setprio(0);
      __builtin_amdgcn_sched_barrier(0);

      if (++sl >= 3) sl = 0;
    }
#undef STAGE_T

    #pragma unroll
    for (int m = 0; m < 2; ++m)
      #pragma unroll
      for (int n = 0; n < 2; ++n)
        #pragma unroll
        for (int r = 0; r < 4; ++r)
          acc2[m][n][r] = __expf(acc2[m][n][r] * INV_T);

    // row sums: each wave's 32-col slice, atomic-accumulated per row
    #pragma unroll
    for (int m = 0; m < 2; ++m) {
      #pragma unroll
      for (int r = 0; r < 4; ++r) {
        float s = acc2[m][0][r] + acc2[m][1][r];
        s += __shfl_xor(s, 1, 64);
        s += __shfl_xor(s, 2, 64);
        s += __shfl_xor(s, 4, 64);
        s += __shfl_xor(s, 8, 64);
        if ((lane & 15) == 0) {
          int grow = row0 + m * 16 + (lane >> 4) * 4 + r;
          atomicAdd(&denom[grow], s);
        }
      }
    }

    // col sums (partial over 32 rows, accumulated across the 8 M-splits)
    if (bi <= 30) {     // band 31's bj=63 tile is in-band: row-sums cover it
      #pragma unroll
      for (int n = 0; n < 2; ++n) {
        float cs = 0.f;
        #pragma unroll
        for (int m = 0; m < 2; ++m)
          #pragma unroll
          for (int r = 0; r < 4; ++r)
            cs += acc2[m][n][r];
        cs += __shfl_xor(cs, 16, 64);
        cs += __shfl_xor(cs, 32, 64);
        if ((lane >> 4) == 0) {
          int gcol = col0 + wave * 32 + n * 16 + (lane & 15);
          atomicAdd(&denom[gcol], cs);
        }
      }
    }
  }
}

// ---------------------------------------------------------------------------
// Kernel 3: loss = mean_i( log(denom_i - exp(self_i/T)) - pos_i/T )
// ---------------------------------------------------------------------------
__global__ __launch_bounds__(256) void loss_k(
    const float* __restrict__ denom, const float* __restrict__ pos,
    const float* __restrict__ selfd, float* __restrict__ out)
{
  const int t = threadIdx.x;
  float acc = 0.f;
  for (int i = t; i < N_ROWS; i += 256) {
    float d = denom[i] - __expf(selfd[i] * INV_T);
    acc += __logf(d) - pos[i] * INV_T;
  }
  #pragma unroll
  for (int m = 1; m < 64; m <<= 1) acc += __shfl_xor(acc, m, 64);
  __shared__ float red[4];
  if ((t & 63) == 0) red[t >> 6] = acc;
  __syncthreads();
  if (t == 0) out[0] = (red[0] + red[1] + red[2] + red[3]) / (float)N_ROWS;
}

// ---------------------------------------------------------------------------
extern "C" void kernel_launch(void* const* d_in, const int* in_sizes, int n_in,
                              void* d_out, int out_size, void* d_ws, size_t ws_size,
                              hipStream_t stream) {
  const float* xi = (const float*)d_in[0];
  const float* xj = (const float*)d_in[1];
  float* out = (float*)d_out;

  char*  ws    = (char*)d_ws;
  short* zb    = (short*)ws;                                   // 32 MiB bf16 z
  float* denom = (float*)(ws + (size_t)N_ROWS * DIM * 2);      // 8192 f32
  float* pos   = denom + N_ROWS;                               // 8192 f32
  float* selfd = pos + N_ROWS;                                 // 8192 f32

  hipMemsetAsync(denom, 0, N_ROWS * sizeof(float), stream);
  normpos_k<<<N_HALF, 256, 0, stream>>>(xi, xj, zb, pos, selfd);
  simexp_k<<<NG1 + NG2, 256, 0, stream>>>(zb, denom);
  loss_k<<<1, 256, 0, stream>>>(denom, pos, selfd, out);
}